// Round 2
// baseline (1159.624 us; speedup 1.0000x reference)
//
#include <hip/hip_runtime.h>
#include <stdint.h>

typedef unsigned short u16;
typedef __attribute__((ext_vector_type(8))) short short8;
typedef __attribute__((ext_vector_type(4))) float floatx4;

#define D_IN  512
#define M_TOT 24000
#define V_DIM 4000
#define V_PAD 4096
#define T_DIM 150
#define U_DIM 40

__device__ __forceinline__ u16 f2bf(float f) {
    union { float f; uint32_t u; } v; v.f = f;
    uint32_t r = v.u + 0x7FFF + ((v.u >> 16) & 1);   // RNE
    return (u16)(r >> 16);
}

// ---------------------------------------------------------------------------
// Kernel 1: enc = enc_state @ W_enc^T + b_enc   [600,512]
//           dec = dec_state @ W_prd^T + b_prd   [160,512]
// grid (8, 24): x = N-tile (64 cols), y<19 enc M-tiles (32 rows), y>=19 dec
// ---------------------------------------------------------------------------
__global__ void k_pre(const float* __restrict__ enc_state, const float* __restrict__ dec_state,
                      const float* __restrict__ W_enc, const float* __restrict__ b_enc,
                      const float* __restrict__ W_prd, const float* __restrict__ b_prd,
                      float* __restrict__ enc_o, float* __restrict__ dec_o)
{
    const float* Ag; const float* Wg; const float* bg; float* Og; int M;
    int by = blockIdx.y;
    if (by < 19) { Ag = enc_state; Wg = W_enc; bg = b_enc; Og = enc_o; M = 600; }
    else         { Ag = dec_state; Wg = W_prd; bg = b_prd; Og = dec_o; M = 160; by -= 19; }

    const int row0 = by * 32;
    const int col0 = blockIdx.x * 64;
    __shared__ float Ash[32][17];
    __shared__ float Bsh[64][17];
    const int tid = threadIdx.x;
    const int tr = tid & 31;
    const int tc = tid >> 5;
    float accv[8] = {0.f,0.f,0.f,0.f,0.f,0.f,0.f,0.f};

    for (int k0 = 0; k0 < D_IN; k0 += 16) {
        __syncthreads();
        #pragma unroll
        for (int s = 0; s < 2; ++s) {
            int idx = tid + s * 256;
            int r = idx >> 4, c = idx & 15;
            Ash[r][c] = (row0 + r < M) ? Ag[(size_t)(row0 + r) * D_IN + k0 + c] : 0.f;
        }
        #pragma unroll
        for (int s = 0; s < 4; ++s) {
            int idx = tid + s * 256;
            int r = idx >> 4, c = idx & 15;
            Bsh[r][c] = Wg[(size_t)(col0 + r) * D_IN + k0 + c];
        }
        __syncthreads();
        #pragma unroll
        for (int kk = 0; kk < 16; ++kk) {
            float a = Ash[tr][kk];
            #pragma unroll
            for (int j = 0; j < 8; ++j) accv[j] += a * Bsh[tc * 8 + j][kk];
        }
    }
    if (row0 + tr < M) {
        #pragma unroll
        for (int j = 0; j < 8; ++j)
            Og[(size_t)(row0 + tr) * D_IN + col0 + tc * 8 + j] = accv[j] + bg[col0 + tc * 8 + j];
    }
}

// ---------------------------------------------------------------------------
// Kernel 2: W_proj [4000,512] fp32 -> bf16 [4096,512], zero pad rows.
// 8 elems / thread (16B stores). grid 1024 * 256 thr * 8 = 4096*512 exact.
// ---------------------------------------------------------------------------
__global__ void k_wconv(const float* __restrict__ W_proj, u16* __restrict__ Wp)
{
    int gid = blockIdx.x * 256 + threadIdx.x;
    int idx8 = gid * 8;
    int row = idx8 >> 9;
    short8 w;
    if (row < V_DIM) {
        const float* p = W_proj + idx8;
        #pragma unroll
        for (int j = 0; j < 8; ++j) w[j] = (short)f2bf(p[j]);
    } else {
        w = (short8){0,0,0,0,0,0,0,0};
    }
    *(short8*)&Wp[idx8] = w;
}

// ---------------------------------------------------------------------------
// Kernel 3: joint[m,i] = tanh(enc[b,t,i] + dec[b,u,i]) -> bf16 [24000,512]
// 4 rows / block, 8 elems / thread, 16B coalesced loads+stores
// ---------------------------------------------------------------------------
__global__ void k_joint(const float* __restrict__ enc_o, const float* __restrict__ dec_o,
                        u16* __restrict__ J)
{
    int m = blockIdx.x * 4 + (threadIdx.x >> 6);
    int i = (threadIdx.x & 63) * 8;
    int b = m / (T_DIM * U_DIM);
    int r = m % (T_DIM * U_DIM);
    int t = r / U_DIM, u = r % U_DIM;
    const float4* e = (const float4*)(enc_o + (size_t)(b * T_DIM + t) * D_IN + i);
    const float4* d = (const float4*)(dec_o + (size_t)(b * U_DIM + u) * D_IN + i);
    float4 e0 = e[0], e1 = e[1], d0 = d[0], d1 = d[1];
    short8 w;
    w[0] = (short)f2bf(tanhf(e0.x + d0.x));
    w[1] = (short)f2bf(tanhf(e0.y + d0.y));
    w[2] = (short)f2bf(tanhf(e0.z + d0.z));
    w[3] = (short)f2bf(tanhf(e0.w + d0.w));
    w[4] = (short)f2bf(tanhf(e1.x + d1.x));
    w[5] = (short)f2bf(tanhf(e1.y + d1.y));
    w[6] = (short)f2bf(tanhf(e1.z + d1.z));
    w[7] = (short)f2bf(tanhf(e1.w + d1.w));
    *(short8*)&J[(size_t)m * D_IN + i] = w;
}

// ---------------------------------------------------------------------------
// Kernel 4 (fused GEMM + log-softmax):
// Each block owns 16 COMPLETE output rows (all 4096 cols in registers), so
// the LSE is computed in-register and C is written exactly ONCE (nt stores).
// 512 threads = 8 waves; wave w owns cols [w*512, (w+1)*512).
// Register budget (deliberate, to avoid spill): acc[32] floatx4 = 128 VGPR,
// A-frags NOT hoisted (re-read from LDS per col-tile), B/A staged in chunks
// of 4 (32 VGPR transient) -> ~180 VGPR total, 0 scratch.
// B streamed from global (Wp bf16 = 4MB = one XCD L2); per-block L2 read 4MB,
// aggregate 6GB / 34.5TB/s ~= 174us = the design ceiling of this kernel.
// ---------------------------------------------------------------------------
__global__ __launch_bounds__(512, 2) void k_fused(const u16* __restrict__ J,
                                                  const u16* __restrict__ Bt,
                                                  const float* __restrict__ bias,
                                                  float* __restrict__ C)
{
    __shared__ u16 Alds[64 * 17 * 8];     // 17408 B, fragment-major, pad 17
    __shared__ float sered[8][16];
    const int tid  = threadIdx.x;
    const int row0 = blockIdx.x * 16;     // grid=1500: 24000 = 1500*16 exact
    const int wave = tid >> 6;
    const int lane = tid & 63;
    const int lrow = lane & 15;           // A-row / B-row(=output col) in frag
    const int lq   = lane >> 4;           // k-quarter; output row = lq*4+reg
    const int wc0  = wave << 9;           // wave col base

    // ---- stage A (16 rows x 512 k bf16 = 16KB) coalesced, fragment-major ----
    #pragma unroll
    for (int s = 0; s < 2; ++s) {
        int c = tid + s * 512;            // 0..1023
        int row = c >> 6, kch = c & 63;   // 64 consecutive threads = 1 row
        *(short8*)&Alds[(kch * 17 + row) * 8] =
            *(const short8*)(J + (size_t)(row0 + row) * D_IN + kch * 8);
    }
    __syncthreads();

    floatx4 acc[32];
    #pragma unroll
    for (int ct = 0; ct < 32; ++ct) acc[ct] = (floatx4){0.f, 0.f, 0.f, 0.f};

    // ---- K-loop: A-frags from LDS, B streamed from L2, 16 MFMA per col-tile
    const u16* bbase = Bt + (size_t)(wc0 + lrow) * D_IN + lq * 8;
    #pragma unroll
    for (int ct = 0; ct < 32; ++ct) {
        if (wc0 + ct * 16 < V_DIM) {      // wave 7, ct>=26: pad cols, skip
            const u16* bp = bbase + (size_t)ct * 16 * D_IN;
            #pragma unroll
            for (int kc = 0; kc < 4; ++kc) {
                short8 afr[4], bfr[4];
                #pragma unroll
                for (int j = 0; j < 4; ++j) {
                    int kk = kc * 4 + j;
                    bfr[j] = *(const short8*)(bp + kk * 32);
                    afr[j] = *(const short8*)&Alds[(((kk << 2) + lq) * 17 + lrow) * 8];
                }
                #pragma unroll
                for (int j = 0; j < 4; ++j)
                    acc[ct] = __builtin_amdgcn_mfma_f32_16x16x32_bf16(afr[j], bfr[j], acc[ct], 0, 0, 0);
            }
        }
    }

    // ---- epilogue: bias + per-lane exp-sums (4 rows x up-to-32 cols each) ----
    float se[4] = {0.f, 0.f, 0.f, 0.f};
    #pragma unroll
    for (int ct = 0; ct < 32; ++ct) {
        int cc = wc0 + ct * 16;
        if (cc < V_DIM) {
            float bv = bias[cc + lrow];
            #pragma unroll
            for (int r = 0; r < 4; ++r) {
                float lg = acc[ct][r] + bv;
                acc[ct][r] = lg;
                se[r] += __expf(lg);
            }
        }
    }
    // reduce across the 16 lanes of each row-group (masks 1..8 stay in-group)
    #pragma unroll
    for (int m = 1; m < 16; m <<= 1) {
        #pragma unroll
        for (int r = 0; r < 4; ++r) se[r] += __shfl_xor(se[r], m, 64);
    }
    if (lrow == 0) {
        #pragma unroll
        for (int r = 0; r < 4; ++r) sered[wave][lq * 4 + r] = se[r];
    }
    __syncthreads();
    float lse[4];
    #pragma unroll
    for (int r = 0; r < 4; ++r) {
        float tot = 0.f;
        #pragma unroll
        for (int w = 0; w < 8; ++w) tot += sered[w][lq * 4 + r];
        lse[r] = __logf(tot);
    }

    // ---- single write of C (nontemporal: never re-read, keep Wp in L2) ----
    float* crow = C + (size_t)(row0 + lq * 4) * V_DIM + lrow;
    #pragma unroll
    for (int ct = 0; ct < 32; ++ct) {
        int cc = wc0 + ct * 16;
        if (cc < V_DIM) {
            #pragma unroll
            for (int r = 0; r < 4; ++r)
                __builtin_nontemporal_store(acc[ct][r] - lse[r], crow + (size_t)r * V_DIM + cc);
        }
    }
}

extern "C" void kernel_launch(void* const* d_in, const int* in_sizes, int n_in,
                              void* d_out, int out_size, void* d_ws, size_t ws_size,
                              hipStream_t stream)
{
    const float* enc_state = (const float*)d_in[0];
    const float* dec_state = (const float*)d_in[1];
    const float* W_enc     = (const float*)d_in[2];
    const float* b_enc     = (const float*)d_in[3];
    const float* W_prd     = (const float*)d_in[4];
    const float* b_prd     = (const float*)d_in[5];
    const float* W_proj    = (const float*)d_in[6];
    const float* b_proj    = (const float*)d_in[7];
    float* out = (float*)d_out;

    char* ws = (char*)d_ws;
    float* enc_o = (float*)(ws);                  // 1,228,800 B
    float* dec_o = (float*)(ws + 1228800);        //   327,680 B
    u16*   Wp    = (u16*)  (ws + 1556480);        // 4,194,304 B
    u16*   J     = (u16*)  (ws + 5750784);        // 24,576,000 B (total ~30.3 MB)

    k_pre  <<<dim3(8, 24), 256, 0, stream>>>(enc_state, dec_state, W_enc, b_enc, W_prd, b_prd, enc_o, dec_o);
    k_wconv<<<dim3(1024),  256, 0, stream>>>(W_proj, Wp);
    k_joint<<<dim3(6000),  256, 0, stream>>>(enc_o, dec_o, J);
    k_fused<<<dim3(1500),  512, 0, stream>>>(J, Wp, b_proj, out);
}